// Round 5
// baseline (249.041 us; speedup 1.0000x reference)
//
#include <hip/hip_runtime.h>
#include <hip/hip_bf16.h>
#include <math.h>

#define B_ 8
#define S_ 2048
#define D_ 1024
#define H_ 64
#define M_ (B_*S_)
#define SPLIT 4
#define KPS (S_/SPLIT)   // 512 keys per split

typedef __attribute__((ext_vector_type(8))) short bf16x8;
typedef __attribute__((ext_vector_type(8))) unsigned short u16x8;
typedef __attribute__((ext_vector_type(4))) float f32x4;

__device__ inline unsigned short f2bf(float f) {
    unsigned int u = __builtin_bit_cast(unsigned int, f);
    u += 0x7fffu + ((u >> 16) & 1u);   // round-to-nearest-even
    return (unsigned short)(u >> 16);
}

// async global->LDS, 16B per lane (global side carries the bank swizzle).
__device__ inline void async16(const void* g, void* l) {
    __builtin_amdgcn_global_load_lds((const __attribute__((address_space(1))) void*)g,
                                     (__attribute__((address_space(3))) void*)l, 16, 0, 0);
}

// mask -> multiplicative 1.0/0.0. Layout sniff: jax bool may be 1-byte or int32.
__global__ __launch_bounds__(256) void mask_kernel(const unsigned char* __restrict__ mask,
                                                   float* __restrict__ mmul, int n) {
    int j = blockIdx.x * 256 + threadIdx.x;
    if (j >= n) return;
    bool boolLayout = mask[1] != 0;
    int mv = boolLayout ? (int)mask[j] : ((const int*)mask)[j];
    mmul[j] = mv ? 1.0f : 0.0f;
}

// Transpose W[1024][64] fp32 -> Wt[64][1024] bf16, one matrix per blockIdx.y.
__global__ __launch_bounds__(256) void wprep_kernel(
    const float* __restrict__ Wq, const float* __restrict__ Wk, const float* __restrict__ Wv,
    unsigned short* __restrict__ Wt)
{
    const int m = blockIdx.y;
    const float* W = (m == 0) ? Wq : (m == 1) ? Wk : Wv;
    unsigned short* Wo = Wt + (size_t)m * 64 * 1024;
    __shared__ unsigned short T[64][65];
    const int t = threadIdx.x;
    const int k0 = blockIdx.x * 64;
    #pragma unroll
    for (int i = 0; i < 16; i++) {
        int vi = t + i * 256;
        int kk = vi >> 6, n = vi & 63;
        T[kk][n] = f2bf(W[(size_t)(k0 + kk) * 64 + n]);
    }
    __syncthreads();
    #pragma unroll
    for (int i = 0; i < 4; i++) {
        int vi = t + i * 256;
        int n = vi >> 4, k4 = vi & 15;
        ushort4 u;
        u.x = T[k4*4+0][n]; u.y = T[k4*4+1][n]; u.z = T[k4*4+2][n]; u.w = T[k4*4+3][n];
        *(ushort4*)&Wo[(size_t)n * 1024 + k0 + k4*4] = u;
    }
}

// x[M,1024] @ W[1024,64].
// Round-4 triangulation: R1 (register-B) moved 603 MB at 6.8 TB/s -> the
// vector path saturates at ~6.5-6.8 TB/s chip-wide; R4 (per-chunk
// vmcnt+barrier x32) cut traffic to 300 MB but only 3.6 TB/s (barrier duty
// ~55%). This version: 300 MB traffic AND continuous issue.
//   A: fp32 stream in a 4-deep register pipeline (no reuse).
//   B: staged per SEGMENT (K=128 = 4 chunks) into 2x16KB LDS double buffer.
//      Wave w stages k-unit plane w (lane = row): stage is lane-linear
//      (global_load_lds requirement) and reads are 256B-contiguous per
//      quarter-wave -> zero bank conflicts, no XOR needed.
//   Sync: ONE barrier per segment (8/block, vs 32), preceded by counted
//      vmcnt(8) that certifies this wave's own B(s) planes (own-count-then-
//      barrier makes the cross-wave DMA visible). Per-chunk counted
//      vmcnt(10) keeps >=10 loads in flight; vmcnt(0) only in the tail.
__global__ __launch_bounds__(256) void proj_kernel(
    const float* __restrict__ q, const float* __restrict__ kx, const float* __restrict__ vx,
    const unsigned short* __restrict__ Wt,
    unsigned short* __restrict__ qp, unsigned short* __restrict__ kp, unsigned short* __restrict__ vpT)
{
    __shared__ unsigned short Bb[2][4 * 2048];   // [buf][ch*2048 + u*512 + n*8]

    const int m = blockIdx.y;
    const float* x = (m == 0) ? q : (m == 1) ? kx : vx;
    const unsigned short* Wm = Wt + (size_t)m * 64 * 1024;

    const int t = threadIdx.x;
    const int w = t >> 6, l = t & 63;
    const int lrow = l & 15, quad = l >> 4;
    const int row0 = blockIdx.x * 64;

    // A: row = row0 + w*16 + lrow, k-offset quad*8 within each 32-chunk
    const float* xa = x + (size_t)(row0 + w * 16 + lrow) * D_ + quad * 8;
    // B stage source: row n = lane l, k-unit plane = wave w
    const unsigned short* wsrc = Wm + (size_t)l * 1024 + w * 8;
    // B read base within a chunk: unit = quad, row n = c*16 + lrow
    const int rbase = quad * 512 + lrow * 8;

    f32x4 acc[4] = {};
    f32x4 pa0[4], pa1[4];

#define STAGE_B(s, buf) do { \
    _Pragma("unroll") \
    for (int ch_ = 0; ch_ < 4; ch_++) \
        async16(wsrc + (s) * 128 + ch_ * 32, &Bb[buf][ch_ * 2048 + t * 8]); \
    asm volatile("" ::: "memory"); } while (0)

#define LOAD_A(st, ptr) do { \
    pa0[st] = *(const f32x4*)(ptr); \
    pa1[st] = *(const f32x4*)((ptr) + 4); \
    asm volatile("" ::: "memory"); } while (0)

#define COMPUTE(st, ch, base) do { \
    f32x4 a0_ = pa0[st], a1_ = pa1[st]; \
    bf16x8 af_; \
    af_[0] = (short)f2bf(a0_.x); af_[1] = (short)f2bf(a0_.y); \
    af_[2] = (short)f2bf(a0_.z); af_[3] = (short)f2bf(a0_.w); \
    af_[4] = (short)f2bf(a1_.x); af_[5] = (short)f2bf(a1_.y); \
    af_[6] = (short)f2bf(a1_.z); af_[7] = (short)f2bf(a1_.w); \
    const unsigned short* bp_ = (base) + (ch) * 2048 + rbase; \
    bf16x8 b0_ = *(const bf16x8*)(bp_); \
    bf16x8 b1_ = *(const bf16x8*)(bp_ + 128); \
    bf16x8 b2_ = *(const bf16x8*)(bp_ + 256); \
    bf16x8 b3_ = *(const bf16x8*)(bp_ + 384); \
    acc[0] = __builtin_amdgcn_mfma_f32_16x16x32_bf16(af_, b0_, acc[0], 0, 0, 0); \
    acc[1] = __builtin_amdgcn_mfma_f32_16x16x32_bf16(af_, b1_, acc[1], 0, 0, 0); \
    acc[2] = __builtin_amdgcn_mfma_f32_16x16x32_bf16(af_, b2_, acc[2], 0, 0, 0); \
    acc[3] = __builtin_amdgcn_mfma_f32_16x16x32_bf16(af_, b3_, acc[3], 0, 0, 0); } while (0)

    // prologue: B(0), A chunks 0..3, B(1)   [issue order pinned by fences]
    STAGE_B(0, 0);
    LOAD_A(0, xa + 0);
    LOAD_A(1, xa + 32);
    LOAD_A(2, xa + 64);
    LOAD_A(3, xa + 96);
    STAGE_B(1, 1);

    // ---- segment 0 ----
    // vmcnt(4): B(0)+A(0..3) complete, only B(1)'s 4 DMAs in flight.
    asm volatile("s_waitcnt vmcnt(4)\n\ts_barrier" ::: "memory");
    {
        const unsigned short* base = &Bb[0][0];
        const float* xk = xa + 128;
        COMPUTE(0, 0, base); LOAD_A(0, xk + 0);
        COMPUTE(1, 1, base); LOAD_A(1, xk + 32);
        COMPUTE(2, 2, base); LOAD_A(2, xk + 64);
        COMPUTE(3, 3, base); LOAD_A(3, xk + 96);
    }

    // ---- segments 1..6 ----
    // Top wait vmcnt(8): after own B(s) came exactly 8 A-refills -> B(s)
    // certified; barrier makes all waves' planes visible + buffer-overwrite
    // safe. Per-chunk vmcnt(10): A(s,c) has exactly 10 younger loads.
    #pragma unroll 1
    for (int s = 1; s <= 6; ++s) {
        const unsigned short* base = &Bb[s & 1][0];
        const float* xk = xa + (s + 1) * 128;
        asm volatile("s_waitcnt vmcnt(8)\n\ts_barrier" ::: "memory");
        STAGE_B(s + 1, (s + 1) & 1);
        asm volatile("s_waitcnt vmcnt(10)" ::: "memory");
        COMPUTE(0, 0, base); LOAD_A(0, xk + 0);
        asm volatile("s_waitcnt vmcnt(10)" ::: "memory");
        COMPUTE(1, 1, base); LOAD_A(1, xk + 32);
        asm volatile("s_waitcnt vmcnt(10)" ::: "memory");
        COMPUTE(2, 2, base); LOAD_A(2, xk + 64);
        asm volatile("s_waitcnt vmcnt(10)" ::: "memory");
        COMPUTE(3, 3, base); LOAD_A(3, xk + 96);
    }

    // ---- segment 7 (no more staging/refills) ----
    asm volatile("s_waitcnt vmcnt(8)\n\ts_barrier" ::: "memory");
    {
        const unsigned short* base = &Bb[1][0];
        asm volatile("s_waitcnt vmcnt(6)" ::: "memory");
        COMPUTE(0, 0, base);
        asm volatile("s_waitcnt vmcnt(4)" ::: "memory");
        COMPUTE(1, 1, base);
        asm volatile("s_waitcnt vmcnt(2)" ::: "memory");
        COMPUTE(2, 2, base);
        asm volatile("s_waitcnt vmcnt(0)" ::: "memory");
        COMPUTE(3, 3, base);
    }

#undef STAGE_B
#undef LOAD_A
#undef COMPUTE

    const int orow = row0 + w * 16 + quad * 4;
    if (m < 2) {
        unsigned short* outp = (m == 0) ? qp : kp;
        const float sc = (m == 0) ? 0.125f : 1.0f;   // fold attn scale into qp
        #pragma unroll
        for (int c = 0; c < 4; c++)
            #pragma unroll
            for (int rr = 0; rr < 4; rr++)
                outp[(size_t)(orow + rr) * H_ + c * 16 + lrow] = f2bf(acc[c][rr] * sc);
    } else {
        // vpT[b][h][s], s0..s0+3 contiguous per lane -> 8B stores
        const int bb = orow >> 11;
        const int s0 = orow & (S_ - 1);
        #pragma unroll
        for (int c = 0; c < 4; c++) {
            ushort4 u;
            u.x = f2bf(acc[c][0]); u.y = f2bf(acc[c][1]);
            u.z = f2bf(acc[c][2]); u.w = f2bf(acc[c][3]);
            *(ushort4*)&vpT[((size_t)bb * H_ + c * 16 + lrow) * S_ + s0] = u;
        }
    }
}

// Flash attention partial: block = (q-tile 64, batch, key-split). Max-free
// single-pass exp => partials over disjoint key ranges combine by addition.
// K and V^T tiles async-staged (L2-resident -> cheap barrier drain).
__global__ __launch_bounds__(256) void attn_kernel(
    const unsigned short* __restrict__ qp, const unsigned short* __restrict__ kp,
    const unsigned short* __restrict__ vpT, const float* __restrict__ mmul,
    float* __restrict__ po, float* __restrict__ pl)
{
    __shared__ unsigned short Qs[64][72];
    __shared__ unsigned short Ps[64][72];
    __shared__ unsigned short Ks[64 * 64];   // swizzled chunks [key][h]
    __shared__ unsigned short Vt[64 * 64];   // swizzled chunks [h][key]

    const int t = threadIdx.x;
    const int w = t >> 6, l = t & 63;
    const int lrow = l & 15, quad = l >> 4;
    const int b = blockIdx.y, q0 = blockIdx.x * 64, split = blockIdx.z;
    const int key0 = split * KPS;
    const size_t basebs = (size_t)b * S_;
    const unsigned short* vb = vpT + (size_t)b * H_ * S_;

    #pragma unroll
    for (int i = 0; i < 2; i++) {            // Q tile once: 512 16B-chunks
        int p = t + i * 256;
        int r = p >> 3, c8 = p & 7;
        u16x8 u = *(const u16x8*)&qp[(basebs + q0 + r) * H_ + c8 * 8];
        *(u16x8*)&Qs[r][c8 * 8] = u;
    }

    float lsum[4] = {0.f, 0.f, 0.f, 0.f};
    f32x4 o[4] = {};

    for (int kt = 0; kt < KPS / 64; kt++) {
        const int k0 = key0 + kt * 64;
        __syncthreads();                     // prev tile's LDS reads done
        #pragma unroll
        for (int j = 0; j < 2; j++) {        // K tile: 512 chunks
            int p = (w * 2 + j) * 64 + l;
            int r = p >> 3;
            int c8 = (p & 7) ^ (r & 7);
            async16(&kp[(basebs + k0 + r) * H_ + c8 * 8], &Ks[p * 8]);
        }
        #pragma unroll
        for (int j = 0; j < 2; j++) {        // V^T tile: 512 chunks
            int p = (w * 2 + j) * 64 + l;
            int h = p >> 3;
            int c8 = (p & 7) ^ (h & 7);
            async16(&vb[(size_t)h * S_ + k0 + c8 * 8], &Vt[p * 8]);
        }
        float mm[4];
        #pragma unroll
        for (int c = 0; c < 4; c++) mm[c] = mmul[basebs + k0 + c*16 + lrow];
        __syncthreads();                     // drain async queue

        // S = Q K^T (pre-scaled by 1/8 via qp)
        f32x4 s[4] = {};
        #pragma unroll
        for (int kk = 0; kk < 2; kk++) {
            bf16x8 aq = *(const bf16x8*)&Qs[w*16 + lrow][kk*32 + quad*8];
            #pragma unroll
            for (int c = 0; c < 4; c++) {
                const int n = c*16 + lrow;
                bf16x8 bk = *(const bf16x8*)&Ks[(n * 8 + ((kk*4 + quad) ^ (n & 7))) * 8];
                s[c] = __builtin_amdgcn_mfma_f32_16x16x32_bf16(aq, bk, s[c], 0, 0, 0);
            }
        }
        // single-pass softmax numerator; sum deferred
        #pragma unroll
        for (int r = 0; r < 4; r++) {
            float p0 = __expf(s[0][r]) * mm[0];
            float p1 = __expf(s[1][r]) * mm[1];
            float p2 = __expf(s[2][r]) * mm[2];
            float p3 = __expf(s[3][r]) * mm[3];
            lsum[r] += (p0 + p1) + (p2 + p3);
            const int pr = w*16 + quad*4 + r;
            Ps[pr][ 0 + lrow] = f2bf(p0);
            Ps[pr][16 + lrow] = f2bf(p1);
            Ps[pr][32 + lrow] = f2bf(p2);
            Ps[pr][48 + lrow] = f2bf(p3);
        }
        // Ps rows [w*16, w*16+16) wave-local: no barrier needed
        #pragma unroll
        for (int kk = 0; kk < 2; kk++) {
            bf16x8 ap = *(const bf16x8*)&Ps[w*16 + lrow][kk*32 + quad*8];
            #pragma unroll
            for (int c = 0; c < 4; c++) {
                const int h = c*16 + lrow;
                bf16x8 bv = *(const bf16x8*)&Vt[(h * 8 + ((kk*4 + quad) ^ (h & 7))) * 8];
                o[c] = __builtin_amdgcn_mfma_f32_16x16x32_bf16(ap, bv, o[c], 0, 0, 0);
            }
        }
    }

    float* pob = po + (size_t)split * M_ * H_;
    float* plb = pl + (size_t)split * M_;
    #pragma unroll
    for (int r = 0; r < 4; r++) {
        #pragma unroll
        for (int d = 1; d < 16; d <<= 1)
            lsum[r] += __shfl_xor(lsum[r], d, 64);
        const size_t row = basebs + q0 + w*16 + quad*4 + r;
        if (lrow == 0) plb[row] = lsum[r];
        #pragma unroll
        for (int c = 0; c < 4; c++)
            pob[row * H_ + c*16 + lrow] = o[c][r];
    }
}

// out = (sum_s po[s]) / (sum_s pl[s]); one float4 per thread.
__global__ __launch_bounds__(256) void combine_kernel(
    const float* __restrict__ po, const float* __restrict__ pl, float* __restrict__ out)
{
    const int idx = blockIdx.x * 256 + threadIdx.x;
    const size_t row = idx >> 4;
    const int c4 = (idx & 15) * 4;
    float lt = 0.f;
    #pragma unroll
    for (int s = 0; s < SPLIT; s++) lt += pl[(size_t)s * M_ + row];
    f32x4 acc = {};
    #pragma unroll
    for (int s = 0; s < SPLIT; s++) {
        const f32x4 p = *(const f32x4*)&po[((size_t)s * M_ + row) * H_ + c4];
        acc += p;
    }
    const float inv = 1.0f / lt;
    f32x4 r = acc * inv;
    *(f32x4*)&out[row * H_ + c4] = r;
}

extern "C" void kernel_launch(void* const* d_in, const int* in_sizes, int n_in,
                              void* d_out, int out_size, void* d_ws, size_t ws_size,
                              hipStream_t stream) {
    const float* q  = (const float*)d_in[0];
    const float* k  = (const float*)d_in[1];
    const float* v  = (const float*)d_in[2];
    const unsigned char* mask = (const unsigned char*)d_in[3];
    const float* Wq = (const float*)d_in[4];
    const float* Wk = (const float*)d_in[5];
    const float* Wv = (const float*)d_in[6];
    float* out = (float*)d_out;

    unsigned short* qp  = (unsigned short*)d_ws;         // 2 MB
    unsigned short* kp  = qp + (size_t)M_ * H_;          // 2 MB
    unsigned short* vpT = kp + (size_t)M_ * H_;          // 2 MB, [b][h][s]
    float* mmul = (float*)(vpT + (size_t)M_ * H_);       // 64 KB
    unsigned short* Wt = (unsigned short*)(mmul + M_);   // 384 KB
    float* po = (float*)(Wt + (size_t)3 * 64 * 1024);    // 16.8 MB
    float* pl = po + (size_t)SPLIT * M_ * H_;            // 256 KB

    wprep_kernel<<<dim3(16, 3), dim3(256), 0, stream>>>(Wq, Wk, Wv, Wt);
    mask_kernel<<<dim3((M_ + 255)/256), dim3(256), 0, stream>>>(mask, mmul, M_);
    proj_kernel<<<dim3(M_/64, 3), dim3(256), 0, stream>>>(q, k, v, Wt, qp, kp, vpT);
    attn_kernel<<<dim3(S_/64, B_, SPLIT), dim3(256), 0, stream>>>(qp, kp, vpT, mmul, po, pl);
    combine_kernel<<<dim3(M_*16/256), dim3(256), 0, stream>>>(po, pl, out);
}

// Round 6
// 239.338 us; speedup vs baseline: 1.0405x; 1.0405x over previous
//
#include <hip/hip_runtime.h>
#include <hip/hip_bf16.h>
#include <math.h>

#define B_ 8
#define S_ 2048
#define D_ 1024
#define H_ 64
#define M_ (B_*S_)
#define SPLIT 4
#define KPS (S_/SPLIT)   // 512 keys per split

typedef __attribute__((ext_vector_type(8))) short bf16x8;
typedef __attribute__((ext_vector_type(8))) unsigned short u16x8;
typedef __attribute__((ext_vector_type(4))) float f32x4;

__device__ inline unsigned short f2bf(float f) {
    unsigned int u = __builtin_bit_cast(unsigned int, f);
    u += 0x7fffu + ((u >> 16) & 1u);   // round-to-nearest-even
    return (unsigned short)(u >> 16);
}

// async global->LDS, 16B per lane (global side carries the bank swizzle).
__device__ inline void async16(const void* g, void* l) {
    __builtin_amdgcn_global_load_lds((const __attribute__((address_space(1))) void*)g,
                                     (__attribute__((address_space(3))) void*)l, 16, 0, 0);
}

// mask -> multiplicative 1.0/0.0. Layout sniff: jax bool may be 1-byte or int32.
__global__ __launch_bounds__(256) void mask_kernel(const unsigned char* __restrict__ mask,
                                                   float* __restrict__ mmul, int n) {
    int j = blockIdx.x * 256 + threadIdx.x;
    if (j >= n) return;
    bool boolLayout = mask[1] != 0;
    int mv = boolLayout ? (int)mask[j] : ((const int*)mask)[j];
    mmul[j] = mv ? 1.0f : 0.0f;
}

// Transpose W[1024][64] fp32 -> Wt[64][1024] bf16, one matrix per blockIdx.y.
__global__ __launch_bounds__(256) void wprep_kernel(
    const float* __restrict__ Wq, const float* __restrict__ Wk, const float* __restrict__ Wv,
    unsigned short* __restrict__ Wt)
{
    const int m = blockIdx.y;
    const float* W = (m == 0) ? Wq : (m == 1) ? Wk : Wv;
    unsigned short* Wo = Wt + (size_t)m * 64 * 1024;
    __shared__ unsigned short T[64][65];
    const int t = threadIdx.x;
    const int k0 = blockIdx.x * 64;
    #pragma unroll
    for (int i = 0; i < 16; i++) {
        int vi = t + i * 256;
        int kk = vi >> 6, n = vi & 63;
        T[kk][n] = f2bf(W[(size_t)(k0 + kk) * 64 + n]);
    }
    __syncthreads();
    #pragma unroll
    for (int i = 0; i < 4; i++) {
        int vi = t + i * 256;
        int n = vi >> 4, k4 = vi & 15;
        ushort4 u;
        u.x = T[k4*4+0][n]; u.y = T[k4*4+1][n]; u.z = T[k4*4+2][n]; u.w = T[k4*4+3][n];
        *(ushort4*)&Wo[(size_t)n * 1024 + k0 + k4*4] = u;
    }
}

// x[M,1024] @ W[1024,64].
// Round-5 post-mortem: FIVE structurally different projs (traffic 300-603MB,
// barriers 8-32, VGPR 44-156) all land at 81-95us, and L3-resident replays
// are equally slow. The invariant is the A PHASE PATTERN: x rows are exactly
// 4KB apart, so in-page offset == k*4; all 768 blocks walk k in lockstep ->
// at any instant the whole chip's A loads target a ~256B band of the 4KB
// page phase. Channel/L3-slice select uses those low bits -> 1-2 of ~32
// channels active -> ~16% HBM regardless of kernel structure.
// Fix: per-block k-phase rotation. Logical segment s -> physical (s+rs)&7
// (512B steps); logical chunk c -> physical c^rc (128B steps); rs,rc from a
// per-block hash -> 32 phases cover the full 4KB page. Accumulation over k
// is order-invariant. LDS slots stay logical (compile-time offsets); only
// the uniform global offsets rotate. Sync schedule identical to round 5:
//   A: fp32 stream, 4-stage register pipeline.
//   B: per-segment (K=128) stage into 2x16KB LDS dbuf, wave w stages k-unit
//      plane w, lane = row: stage lane-linear, reads 256B-contiguous per
//      quarter-wave -> zero bank conflicts (confirmed: counter = 0).
//   One barrier per segment w/ counted vmcnt(8); per-chunk vmcnt(10);
//   vmcnt(0) only in the tail.
__global__ __launch_bounds__(256) void proj_kernel(
    const float* __restrict__ q, const float* __restrict__ kx, const float* __restrict__ vx,
    const unsigned short* __restrict__ Wt,
    unsigned short* __restrict__ qp, unsigned short* __restrict__ kp, unsigned short* __restrict__ vpT)
{
    __shared__ unsigned short Bb[2][4 * 2048];   // [buf][ch*2048 + u*512 + n*8]

    const int m = blockIdx.y;
    const float* x = (m == 0) ? q : (m == 1) ? kx : vx;
    const unsigned short* Wm = Wt + (size_t)m * 64 * 1024;

    const int t = threadIdx.x;
    const int w = t >> 6, l = t & 63;
    const int lrow = l & 15, quad = l >> 4;
    const int row0 = blockIdx.x * 64;

    // per-block k-phase rotation (block-uniform scalars)
    const int rot = (blockIdx.x * 5 + m * 11) & 31;
    const int rs = rot >> 2;   // segment rotation 0..7  (512B phase steps)
    const int rc = rot & 3;    // chunk XOR 0..3         (128B phase steps)

    // A: row = row0 + w*16 + lrow, k-offset quad*8 within each 32-chunk
    const float* xa = x + (size_t)(row0 + w * 16 + lrow) * D_ + quad * 8;
    // B stage source: row n = lane l, k-unit plane = wave w
    const unsigned short* wsrc = Wm + (size_t)l * 1024 + w * 8;
    // B read base within a chunk slot: unit = quad, row n = c*16 + lrow
    const int rbase = quad * 512 + lrow * 8;

    f32x4 acc[4] = {};
    f32x4 pa0[4], pa1[4];

    // float/element offset of logical (segment s, chunk c) after rotation
#define GOFF(s, c) ((((s) + rs) & 7) * 128 + (((c) ^ rc)) * 32)

#define STAGE_B(s, buf) do { \
    _Pragma("unroll") \
    for (int ch_ = 0; ch_ < 4; ch_++) \
        async16(wsrc + GOFF(s, ch_), &Bb[buf][ch_ * 2048 + t * 8]); \
    asm volatile("" ::: "memory"); } while (0)

#define LOAD_A(st, s, c) do { \
    pa0[st] = *(const f32x4*)(xa + GOFF(s, c)); \
    pa1[st] = *(const f32x4*)(xa + GOFF(s, c) + 4); \
    asm volatile("" ::: "memory"); } while (0)

#define COMPUTE(st, ch, base) do { \
    f32x4 a0_ = pa0[st], a1_ = pa1[st]; \
    bf16x8 af_; \
    af_[0] = (short)f2bf(a0_.x); af_[1] = (short)f2bf(a0_.y); \
    af_[2] = (short)f2bf(a0_.z); af_[3] = (short)f2bf(a0_.w); \
    af_[4] = (short)f2bf(a1_.x); af_[5] = (short)f2bf(a1_.y); \
    af_[6] = (short)f2bf(a1_.z); af_[7] = (short)f2bf(a1_.w); \
    const unsigned short* bp_ = (base) + (ch) * 2048 + rbase; \
    bf16x8 b0_ = *(const bf16x8*)(bp_); \
    bf16x8 b1_ = *(const bf16x8*)(bp_ + 128); \
    bf16x8 b2_ = *(const bf16x8*)(bp_ + 256); \
    bf16x8 b3_ = *(const bf16x8*)(bp_ + 384); \
    acc[0] = __builtin_amdgcn_mfma_f32_16x16x32_bf16(af_, b0_, acc[0], 0, 0, 0); \
    acc[1] = __builtin_amdgcn_mfma_f32_16x16x32_bf16(af_, b1_, acc[1], 0, 0, 0); \
    acc[2] = __builtin_amdgcn_mfma_f32_16x16x32_bf16(af_, b2_, acc[2], 0, 0, 0); \
    acc[3] = __builtin_amdgcn_mfma_f32_16x16x32_bf16(af_, b3_, acc[3], 0, 0, 0); } while (0)

    // prologue: B(0), A segment-0 chunks 0..3, B(1)  [order pinned by fences]
    STAGE_B(0, 0);
    LOAD_A(0, 0, 0);
    LOAD_A(1, 0, 1);
    LOAD_A(2, 0, 2);
    LOAD_A(3, 0, 3);
    STAGE_B(1, 1);

    // ---- segment 0 ----
    // vmcnt(4): B(0)+A(0,*) complete, only B(1)'s 4 DMAs in flight.
    asm volatile("s_waitcnt vmcnt(4)\n\ts_barrier" ::: "memory");
    {
        const unsigned short* base = &Bb[0][0];
        COMPUTE(0, 0, base); LOAD_A(0, 1, 0);
        COMPUTE(1, 1, base); LOAD_A(1, 1, 1);
        COMPUTE(2, 2, base); LOAD_A(2, 1, 2);
        COMPUTE(3, 3, base); LOAD_A(3, 1, 3);
    }

    // ---- segments 1..6 ----
    // Top wait vmcnt(8): after own B(s) came exactly 8 A-refills -> B(s)
    // certified; barrier makes all waves' planes visible + buffer-overwrite
    // safe. Per-chunk vmcnt(10): A(s,c) has exactly 10 younger loads.
    #pragma unroll 1
    for (int s = 1; s <= 6; ++s) {
        const unsigned short* base = &Bb[s & 1][0];
        asm volatile("s_waitcnt vmcnt(8)\n\ts_barrier" ::: "memory");
        STAGE_B(s + 1, (s + 1) & 1);
        asm volatile("s_waitcnt vmcnt(10)" ::: "memory");
        COMPUTE(0, 0, base); LOAD_A(0, s + 1, 0);
        asm volatile("s_waitcnt vmcnt(10)" ::: "memory");
        COMPUTE(1, 1, base); LOAD_A(1, s + 1, 1);
        asm volatile("s_waitcnt vmcnt(10)" ::: "memory");
        COMPUTE(2, 2, base); LOAD_A(2, s + 1, 2);
        asm volatile("s_waitcnt vmcnt(10)" ::: "memory");
        COMPUTE(3, 3, base); LOAD_A(3, s + 1, 3);
    }

    // ---- segment 7 (no more staging/refills) ----
    asm volatile("s_waitcnt vmcnt(8)\n\ts_barrier" ::: "memory");
    {
        const unsigned short* base = &Bb[1][0];
        asm volatile("s_waitcnt vmcnt(6)" ::: "memory");
        COMPUTE(0, 0, base);
        asm volatile("s_waitcnt vmcnt(4)" ::: "memory");
        COMPUTE(1, 1, base);
        asm volatile("s_waitcnt vmcnt(2)" ::: "memory");
        COMPUTE(2, 2, base);
        asm volatile("s_waitcnt vmcnt(0)" ::: "memory");
        COMPUTE(3, 3, base);
    }

#undef STAGE_B
#undef LOAD_A
#undef COMPUTE
#undef GOFF

    const int orow = row0 + w * 16 + quad * 4;
    if (m < 2) {
        unsigned short* outp = (m == 0) ? qp : kp;
        const float sc = (m == 0) ? 0.125f : 1.0f;   // fold attn scale into qp
        #pragma unroll
        for (int c = 0; c < 4; c++)
            #pragma unroll
            for (int rr = 0; rr < 4; rr++)
                outp[(size_t)(orow + rr) * H_ + c * 16 + lrow] = f2bf(acc[c][rr] * sc);
    } else {
        // vpT[b][h][s], s0..s0+3 contiguous per lane -> 8B stores
        const int bb = orow >> 11;
        const int s0 = orow & (S_ - 1);
        #pragma unroll
        for (int c = 0; c < 4; c++) {
            ushort4 u;
            u.x = f2bf(acc[c][0]); u.y = f2bf(acc[c][1]);
            u.z = f2bf(acc[c][2]); u.w = f2bf(acc[c][3]);
            *(ushort4*)&vpT[((size_t)bb * H_ + c * 16 + lrow) * S_ + s0] = u;
        }
    }
}

// Flash attention partial: block = (q-tile 64, batch, key-split). Max-free
// single-pass exp => partials over disjoint key ranges combine by addition.
// K and V^T tiles async-staged (L2-resident -> cheap barrier drain).
__global__ __launch_bounds__(256) void attn_kernel(
    const unsigned short* __restrict__ qp, const unsigned short* __restrict__ kp,
    const unsigned short* __restrict__ vpT, const float* __restrict__ mmul,
    float* __restrict__ po, float* __restrict__ pl)
{
    __shared__ unsigned short Qs[64][72];
    __shared__ unsigned short Ps[64][72];
    __shared__ unsigned short Ks[64 * 64];   // swizzled chunks [key][h]
    __shared__ unsigned short Vt[64 * 64];   // swizzled chunks [h][key]

    const int t = threadIdx.x;
    const int w = t >> 6, l = t & 63;
    const int lrow = l & 15, quad = l >> 4;
    const int b = blockIdx.y, q0 = blockIdx.x * 64, split = blockIdx.z;
    const int key0 = split * KPS;
    const size_t basebs = (size_t)b * S_;
    const unsigned short* vb = vpT + (size_t)b * H_ * S_;

    #pragma unroll
    for (int i = 0; i < 2; i++) {            // Q tile once: 512 16B-chunks
        int p = t + i * 256;
        int r = p >> 3, c8 = p & 7;
        u16x8 u = *(const u16x8*)&qp[(basebs + q0 + r) * H_ + c8 * 8];
        *(u16x8*)&Qs[r][c8 * 8] = u;
    }

    float lsum[4] = {0.f, 0.f, 0.f, 0.f};
    f32x4 o[4] = {};

    for (int kt = 0; kt < KPS / 64; kt++) {
        const int k0 = key0 + kt * 64;
        __syncthreads();                     // prev tile's LDS reads done
        #pragma unroll
        for (int j = 0; j < 2; j++) {        // K tile: 512 chunks
            int p = (w * 2 + j) * 64 + l;
            int r = p >> 3;
            int c8 = (p & 7) ^ (r & 7);
            async16(&kp[(basebs + k0 + r) * H_ + c8 * 8], &Ks[p * 8]);
        }
        #pragma unroll
        for (int j = 0; j < 2; j++) {        // V^T tile: 512 chunks
            int p = (w * 2 + j) * 64 + l;
            int h = p >> 3;
            int c8 = (p & 7) ^ (h & 7);
            async16(&vb[(size_t)h * S_ + k0 + c8 * 8], &Vt[p * 8]);
        }
        float mm[4];
        #pragma unroll
        for (int c = 0; c < 4; c++) mm[c] = mmul[basebs + k0 + c*16 + lrow];
        __syncthreads();                     // drain async queue

        // S = Q K^T (pre-scaled by 1/8 via qp)
        f32x4 s[4] = {};
        #pragma unroll
        for (int kk = 0; kk < 2; kk++) {
            bf16x8 aq = *(const bf16x8*)&Qs[w*16 + lrow][kk*32 + quad*8];
            #pragma unroll
            for (int c = 0; c < 4; c++) {
                const int n = c*16 + lrow;
                bf16x8 bk = *(const bf16x8*)&Ks[(n * 8 + ((kk*4 + quad) ^ (n & 7))) * 8];
                s[c] = __builtin_amdgcn_mfma_f32_16x16x32_bf16(aq, bk, s[c], 0, 0, 0);
            }
        }
        // single-pass softmax numerator; sum deferred
        #pragma unroll
        for (int r = 0; r < 4; r++) {
            float p0 = __expf(s[0][r]) * mm[0];
            float p1 = __expf(s[1][r]) * mm[1];
            float p2 = __expf(s[2][r]) * mm[2];
            float p3 = __expf(s[3][r]) * mm[3];
            lsum[r] += (p0 + p1) + (p2 + p3);
            const int pr = w*16 + quad*4 + r;
            Ps[pr][ 0 + lrow] = f2bf(p0);
            Ps[pr][16 + lrow] = f2bf(p1);
            Ps[pr][32 + lrow] = f2bf(p2);
            Ps[pr][48 + lrow] = f2bf(p3);
        }
        // Ps rows [w*16, w*16+16) wave-local: no barrier needed
        #pragma unroll
        for (int kk = 0; kk < 2; kk++) {
            bf16x8 ap = *(const bf16x8*)&Ps[w*16 + lrow][kk*32 + quad*8];
            #pragma unroll
            for (int c = 0; c < 4; c++) {
                const int h = c*16 + lrow;
                bf16x8 bv = *(const bf16x8*)&Vt[(h * 8 + ((kk*4 + quad) ^ (h & 7))) * 8];
                o[c] = __builtin_amdgcn_mfma_f32_16x16x32_bf16(ap, bv, o[c], 0, 0, 0);
            }
        }
    }

    float* pob = po + (size_t)split * M_ * H_;
    float* plb = pl + (size_t)split * M_;
    #pragma unroll
    for (int r = 0; r < 4; r++) {
        #pragma unroll
        for (int d = 1; d < 16; d <<= 1)
            lsum[r] += __shfl_xor(lsum[r], d, 64);
        const size_t row = basebs + q0 + w*16 + quad*4 + r;
        if (lrow == 0) plb[row] = lsum[r];
        #pragma unroll
        for (int c = 0; c < 4; c++)
            pob[row * H_ + c*16 + lrow] = o[c][r];
    }
}

// out = (sum_s po[s]) / (sum_s pl[s]); one float4 per thread.
__global__ __launch_bounds__(256) void combine_kernel(
    const float* __restrict__ po, const float* __restrict__ pl, float* __restrict__ out)
{
    const int idx = blockIdx.x * 256 + threadIdx.x;
    const size_t row = idx >> 4;
    const int c4 = (idx & 15) * 4;
    float lt = 0.f;
    #pragma unroll
    for (int s = 0; s < SPLIT; s++) lt += pl[(size_t)s * M_ + row];
    f32x4 acc = {};
    #pragma unroll
    for (int s = 0; s < SPLIT; s++) {
        const f32x4 p = *(const f32x4*)&po[((size_t)s * M_ + row) * H_ + c4];
        acc += p;
    }
    const float inv = 1.0f / lt;
    f32x4 r = acc * inv;
    *(f32x4*)&out[row * H_ + c4] = r;
}

extern "C" void kernel_launch(void* const* d_in, const int* in_sizes, int n_in,
                              void* d_out, int out_size, void* d_ws, size_t ws_size,
                              hipStream_t stream) {
    const float* q  = (const float*)d_in[0];
    const float* k  = (const float*)d_in[1];
    const float* v  = (const float*)d_in[2];
    const unsigned char* mask = (const unsigned char*)d_in[3];
    const float* Wq = (const float*)d_in[4];
    const float* Wk = (const float*)d_in[5];
    const float* Wv = (const float*)d_in[6];
    float* out = (float*)d_out;

    unsigned short* qp  = (unsigned short*)d_ws;         // 2 MB
    unsigned short* kp  = qp + (size_t)M_ * H_;          // 2 MB
    unsigned short* vpT = kp + (size_t)M_ * H_;          // 2 MB, [b][h][s]
    float* mmul = (float*)(vpT + (size_t)M_ * H_);       // 64 KB
    unsigned short* Wt = (unsigned short*)(mmul + M_);   // 384 KB
    float* po = (float*)(Wt + (size_t)3 * 64 * 1024);    // 16.8 MB
    float* pl = po + (size_t)SPLIT * M_ * H_;            // 256 KB

    wprep_kernel<<<dim3(16, 3), dim3(256), 0, stream>>>(Wq, Wk, Wv, Wt);
    mask_kernel<<<dim3((M_ + 255)/256), dim3(256), 0, stream>>>(mask, mmul, M_);
    proj_kernel<<<dim3(M_/64, 3), dim3(256), 0, stream>>>(q, k, v, Wt, qp, kp, vpT);
    attn_kernel<<<dim3(S_/64, B_, SPLIT), dim3(256), 0, stream>>>(qp, kp, vpT, mmul, po, pl);
    combine_kernel<<<dim3(M_*16/256), dim3(256), 0, stream>>>(po, pl, out);
}